// Round 10
// baseline (777.943 us; speedup 1.0000x reference)
//
#include <hip/hip_runtime.h>
#include <hip/hip_bf16.h>
#include <math.h>

#define Bc   2
#define Nc   10000
#define Ec   100000
#define Hc   128
#define DINc 8
#define DBc  16
#define NBc  3
#define Lc   2

typedef float v4 __attribute__((ext_vector_type(4)));
typedef float f32x16 __attribute__((ext_vector_type(16)));
typedef _Float16 h8 __attribute__((ext_vector_type(8)));
typedef _Float16 h4 __attribute__((ext_vector_type(4)));

__device__ __forceinline__ float silu_f(float x) {
  return x * __builtin_amdgcn_rcpf(1.f + __expf(-x));
}

__device__ __forceinline__ h4 pack4(float a, float b, float c, float d) {
  typedef decltype(__builtin_amdgcn_cvt_pkrtz(0.f, 0.f)) pk2;
  union { h4 v; pk2 p[2]; } u;
  u.p[0] = __builtin_amdgcn_cvt_pkrtz(a, b);
  u.p[1] = __builtin_amdgcn_cvt_pkrtz(c, d);
  return u.v;
}

// ---------------- small utility kernels ----------------

__global__ void zero4_kernel(float* __restrict__ p, int n4) {
  int i = blockIdx.x * blockDim.x + threadIdx.x;
  if (i < n4) ((v4*)p)[i] = (v4)(0.f);
}

__global__ void copy_kernel(float* __restrict__ dst, const float* __restrict__ src, int n) {
  int i = blockIdx.x * blockDim.x + threadIdx.x;
  if (i < n) dst[i] = src[i];
}

// ---------------- sort-by-dst machinery ----------------

__global__ void hist_kernel(int* __restrict__ hist, const int* __restrict__ edst) {
  int i = blockIdx.x * blockDim.x + threadIdx.x;
  if (i < NBc * Ec) {
    int k = i / Ec;
    atomicAdd(&hist[k * Nc + edst[i]], 1);
  }
}

__global__ void scan_kernel(const int* __restrict__ hist, int* __restrict__ offs,
                            float* __restrict__ deginv) {
  const int k = blockIdx.x, tid = threadIdx.x;
  const int NPT = 40;
  __shared__ int part[256];
  int local[NPT];
  int sum = 0;
  for (int j = 0; j < NPT; ++j) {
    int n = tid * NPT + j;
    if (n < Nc) { local[j] = sum; sum += hist[k * Nc + n]; }
  }
  part[tid] = sum;
  __syncthreads();
  for (int off = 1; off < 256; off <<= 1) {
    int v = (tid >= off) ? part[tid - off] : 0;
    __syncthreads();
    part[tid] += v;
    __syncthreads();
  }
  int excl = part[tid] - sum;
  for (int j = 0; j < NPT; ++j) {
    int n = tid * NPT + j;
    if (n < Nc) {
      offs[k * Nc + n] = excl + local[j];
      deginv[k * Nc + n] = 1.f / fmaxf((float)hist[k * Nc + n], 1.f);
    }
  }
}

__global__ void sort_scatter_kernel(int* __restrict__ sorted, int* __restrict__ cursor,
                                    const int* __restrict__ offs, const int* __restrict__ edst) {
  int i = blockIdx.x * blockDim.x + threadIdx.x;
  if (i < NBc * Ec) {
    int k = i / Ec, e = i - k * Ec;
    int d = edst[i];
    int pos = offs[k * Nc + d] + atomicAdd(&cursor[k * Nc + d], 1);
    sorted[k * Ec + pos] = e;
  }
}

// ---------------- init kernels ----------------

__global__ void init_h_kernel(_Float16* __restrict__ h16, const float* __restrict__ bfeat,
                              const float* __restrict__ x, const float* __restrict__ Win,
                              const float* __restrict__ b_in, const int* __restrict__ ent) {
  int g = blockIdx.x * blockDim.x + threadIdx.x;
  if (g >= Bc * Nc * Hc) return;
  int j = g & (Hc - 1);
  int bn = g >> 7;
  int n = bn % Nc;
  int b = bn / Nc;
  float acc = b_in[j];
#pragma unroll
  for (int i = 0; i < DBc; ++i) acc = fmaf(bfeat[n * DBc + i], Win[i * Hc + j], acc);
  if (n == ent[b]) {
#pragma unroll
    for (int i = 0; i < DINc; ++i) acc = fmaf(x[b * DINc + i], Win[(DBc + i) * Hc + j], acc);
  }
  h16[g] = (_Float16)acc;
}

__global__ void init_p_kernel(float* __restrict__ p, const float* __restrict__ bp) {
  int i = blockIdx.x * blockDim.x + threadIdx.x;
  if (i < Bc * Nc * 3) p[i] = bp[i % (Nc * 3)];
}

// ---------------- weight -> extended f16 MFMA-fragment conversion ----------------
__global__ void conv_ext_kernel(_Float16* __restrict__ dst, const float* __restrict__ src,
                                const float* __restrict__ bias,
                                int nchunk, int total, int realRows, int biasRow) {
  int g = blockIdx.x * blockDim.x + threadIdx.x;
  if (g >= total) return;
  int j = g & 7;
  int lane = (g >> 3) & 63;
  int q = g >> 9;
  int t = q % nchunk;
  int q2 = q / nchunk;
  int wave = q2 & 3;
  int mat = q2 >> 2;
  int kk = t * 16 + (lane >> 5) * 8 + j;
  int col = (wave << 5) + (lane & 31);
  float v = 0.f;
  if (kk < realRows)      v = src[((size_t)mat * realRows + kk) * Hc + col];
  else if (kk == biasRow) v = bias[mat * Hc + col];
  dst[g] = (_Float16)v;
}

// ---------------- fused edge MLP kernel (TE=64, reg-hoisted weights) ----------------
// grid (B*E/64 = 3125, NB), 256 threads = 4 waves. All 35 weight fragments for
// this wave loaded into registers at kernel entry (zero VMEM in GEMM loops).
// Dual edge-halves per wave (2 MFMAs per weight reg). m1 in separate Mbuf;
// m2 dual-stored (frag for GEMM3 + swizzled row-major for conflict-free scatter).

__global__ __launch_bounds__(256, 2)
void edge_mfma_kernel(const _Float16* __restrict__ h16, const float* __restrict__ p,
                      float* __restrict__ m_sum, float* __restrict__ p_new,
                      const float* __restrict__ deginv,
                      const int* __restrict__ esrc, const int* __restrict__ edst,
                      const int* __restrict__ sorted,
                      const _Float16* __restrict__ W1e, const _Float16* __restrict__ W2e,
                      const _Float16* __restrict__ P1e,
                      const float* __restrict__ pW2, const float* __restrict__ pb2,
                      int l) {
  const int k = blockIdx.y, lk = l * NBc + k;
  const int tid = threadIdx.x;
  const int wave = tid >> 6, lane = tid & 63;
  const int lrow = lane & 31, lhalf = lane >> 5;

  __shared__ __align__(16) _Float16 RegA[16384];   // acts: 16 chunks x 2 halves x 512 (32KB); m2 frag -> chunks 8-15
  __shared__ __align__(16) _Float16 Mbuf[8192];    // m1: 8 chunks x 2 halves x 512 (16KB)
  __shared__ __align__(16) _Float16 RMbuf[8192];   // m2 row-major swizzled: 64 rows x 128 (16KB)
  __shared__ __align__(16) _Float16 Dchk[1024];
  __shared__ int shd[64], shs[64], snd[64];
  __shared__ float sdinv[64], srel[64][3], scoef[64];
  __shared__ float cpw2[Hc];
  __shared__ unsigned long long sflush;

  // ---- hoist all weight fragments into registers (35 x 16B loads, issued now) ----
  const _Float16* wb1 = &W1e[(size_t)(lk * 4 + wave) * (17 * 512)];
  const _Float16* wb2 = &W2e[(size_t)(lk * 4 + wave) * (9 * 512)];
  const _Float16* wb3 = &P1e[(size_t)(lk * 4 + wave) * (9 * 512)];
  h8 w1r[17], w2r[9], w3r[9];
#pragma unroll
  for (int t = 0; t < 17; ++t) w1r[t] = *(const h8*)&wb1[t * 512 + lane * 8];
#pragma unroll
  for (int t = 0; t < 9; ++t)  w2r[t] = *(const h8*)&wb2[t * 512 + lane * 8];
#pragma unroll
  for (int t = 0; t < 9; ++t)  w3r[t] = *(const h8*)&wb3[t * 512 + lane * 8];

  if (tid < Hc) cpw2[tid] = pW2[lk * Hc + tid];
  if (tid < 64) {
    int pos = blockIdx.x * 64 + tid;
    int b = (pos >= Ec) ? 1 : 0;
    int e = sorted[k * Ec + (pos - b * Ec)];
    int si = esrc[k * Ec + e], di = edst[k * Ec + e];
    int nd = b * Nc + di, ns = b * Nc + si;
    const float* pd = &p[(size_t)nd * 3];
    const float* ps = &p[(size_t)ns * 3];
    float rx = pd[0] - ps[0], ry = pd[1] - ps[1], rz = pd[2] - ps[2];
    srel[tid][0] = rx; srel[tid][1] = ry; srel[tid][2] = rz;
    float d2 = rx * rx + ry * ry + rz * rz;
    sdinv[tid] = deginv[k * Nc + di];
    shd[tid] = nd * Hc; shs[tid] = ns * Hc; snd[tid] = nd;
    scoef[tid] = 0.f;
    h8 dv = (h8)(_Float16)0.f;
    h8 zv = (h8)(_Float16)0.f;
    dv[0] = (_Float16)d2; dv[1] = (_Float16)1.f;
    int g = tid >> 5, il = tid & 31;
    *(h8*)&Dchk[g * 512 + il * 8] = dv;
    *(h8*)&Dchk[g * 512 + 256 + il * 8] = zv;
    int prevn = __shfl_up(nd, 1);
    bool isStart = (tid == 0) || (nd != prevn);
    unsigned long long m = __ballot(isStart);
    if (tid == 0) sflush = (m >> 1) | (1ull << 63);
  }
  __syncthreads();                                   // B1

  h8 dA = *(const h8*)&Dchk[lane * 8];
  h8 dB = *(const h8*)&Dchk[512 + lane * 8];

  // ---- gather h16 rows into frag order ----
  {
    const int i = tid & 63, cg = tid >> 6;
    const int g = i >> 5, il = i & 31;
#pragma unroll
    for (int q = 0; q < 4; ++q) {
      int d0 = cg * 32 + q * 8;
      int t = d0 >> 4;
      int kh = q & 1;
      h8 vd = *(const h8*)&h16[shd[i] + d0];
      h8 vs = *(const h8*)&h16[shs[i] + d0];
      *(h8*)&RegA[(t * 2 + g) * 512 + kh * 256 + il * 8] = vd;
      *(h8*)&RegA[((8 + t) * 2 + g) * 512 + kh * 256 + il * 8] = vs;
    }
  }
  __syncthreads();                                   // B2

  // ---- GEMM1^T: K=272, weights in registers ----
  f32x16 aA, aB;
#pragma unroll
  for (int r = 0; r < 16; ++r) { aA[r] = 0.f; aB[r] = 0.f; }
#pragma unroll
  for (int t = 0; t < 16; ++t) {
    h8 bA = *(const h8*)&RegA[(t * 2 + 0) * 512 + lane * 8];
    h8 bB = *(const h8*)&RegA[(t * 2 + 1) * 512 + lane * 8];
    aA = __builtin_amdgcn_mfma_f32_32x32x16_f16(w1r[t], bA, aA, 0, 0, 0);
    aB = __builtin_amdgcn_mfma_f32_32x32x16_f16(w1r[t], bB, aB, 0, 0, 0);
  }
  aA = __builtin_amdgcn_mfma_f32_32x32x16_f16(w1r[16], dA, aA, 0, 0, 0);
  aB = __builtin_amdgcn_mfma_f32_32x32x16_f16(w1r[16], dB, aB, 0, 0, 0);
  // m1 -> Mbuf (fresh buffer: no WAR barrier needed before writes)
#pragma unroll
  for (int c = 0; c < 4; ++c) {
    h4 m1A = pack4(silu_f(aA[c * 4 + 0]), silu_f(aA[c * 4 + 1]),
                   silu_f(aA[c * 4 + 2]), silu_f(aA[c * 4 + 3]));
    h4 m1B = pack4(silu_f(aB[c * 4 + 0]), silu_f(aB[c * 4 + 1]),
                   silu_f(aB[c * 4 + 2]), silu_f(aB[c * 4 + 3]));
    int t = 2 * wave + (c >> 1);
    int base = (c & 1) * 256 + lrow * 8 + lhalf * 4;
    *(h4*)&Mbuf[(t * 2 + 0) * 512 + base] = m1A;
    *(h4*)&Mbuf[(t * 2 + 1) * 512 + base] = m1B;
  }
  __syncthreads();                                   // B3

  // ---- GEMM2^T: K=144 ----
#pragma unroll
  for (int r = 0; r < 16; ++r) { aA[r] = 0.f; aB[r] = 0.f; }
#pragma unroll
  for (int t = 0; t < 8; ++t) {
    h8 bA = *(const h8*)&Mbuf[(t * 2 + 0) * 512 + lane * 8];
    h8 bB = *(const h8*)&Mbuf[(t * 2 + 1) * 512 + lane * 8];
    aA = __builtin_amdgcn_mfma_f32_32x32x16_f16(w2r[t], bA, aA, 0, 0, 0);
    aB = __builtin_amdgcn_mfma_f32_32x32x16_f16(w2r[t], bB, aB, 0, 0, 0);
  }
  aA = __builtin_amdgcn_mfma_f32_32x32x16_f16(w2r[8], dA, aA, 0, 0, 0);
  aB = __builtin_amdgcn_mfma_f32_32x32x16_f16(w2r[8], dB, aB, 0, 0, 0);
  // m2 -> frag chunks 8-15 (hs dead since B3) + swizzled row-major RMbuf
  {
    char* rm = (char*)RMbuf;
#pragma unroll
    for (int c = 0; c < 4; ++c) {
      h4 p2A = pack4(silu_f(aA[c * 4 + 0]), silu_f(aA[c * 4 + 1]),
                     silu_f(aA[c * 4 + 2]), silu_f(aA[c * 4 + 3]));
      h4 p2B = pack4(silu_f(aB[c * 4 + 0]), silu_f(aB[c * 4 + 1]),
                     silu_f(aB[c * 4 + 2]), silu_f(aB[c * 4 + 3]));
      int t2 = 8 + 2 * wave + (c >> 1);
      int base = (c & 1) * 256 + lrow * 8 + lhalf * 4;
      *(h4*)&RegA[(t2 * 2 + 0) * 512 + base] = p2A;
      *(h4*)&RegA[(t2 * 2 + 1) * 512 + base] = p2B;
      int hb = (wave << 5) + (c << 3) + (lhalf << 2);
      int sw = (lrow & 15) << 4;
      *(h4*)(rm + (lrow << 8) + (((hb << 1)) ^ sw)) = p2A;
      *(h4*)(rm + ((32 + lrow) << 8) + (((hb << 1)) ^ sw)) = p2B;
    }
  }
  __syncthreads();                                   // B4

  // ---- GEMM3^T: q = P1e([m2|1]); coef = sum silu(q)*pW2 ----
#pragma unroll
  for (int r = 0; r < 16; ++r) { aA[r] = 0.f; aB[r] = 0.f; }
#pragma unroll
  for (int t = 0; t < 8; ++t) {
    h8 bA = *(const h8*)&RegA[((8 + t) * 2 + 0) * 512 + lane * 8];
    h8 bB = *(const h8*)&RegA[((8 + t) * 2 + 1) * 512 + lane * 8];
    aA = __builtin_amdgcn_mfma_f32_32x32x16_f16(w3r[t], bA, aA, 0, 0, 0);
    aB = __builtin_amdgcn_mfma_f32_32x32x16_f16(w3r[t], bB, aB, 0, 0, 0);
  }
  aA = __builtin_amdgcn_mfma_f32_32x32x16_f16(w3r[8], dA, aA, 0, 0, 0);
  aB = __builtin_amdgcn_mfma_f32_32x32x16_f16(w3r[8], dB, aB, 0, 0, 0);
  {
    float csA = 0.f, csB = 0.f;
#pragma unroll
    for (int r = 0; r < 16; ++r) {
      int hg = (wave << 5) + (r & 3) + ((r >> 2) << 3) + (lhalf << 2);
      csA += silu_f(aA[r]) * cpw2[hg];
      csB += silu_f(aB[r]) * cpw2[hg];
    }
    csA += __shfl_down(csA, 32);
    csB += __shfl_down(csB, 32);
    if (lane < 32) {
      atomicAdd(&scoef[lrow], csA);
      atomicAdd(&scoef[32 + lrow], csB);
    }
  }

  // ---- segmented m_sum scatter from RMbuf (2 lanes/bank: conflict-free) ----
  {
    const int col = tid & 127;
    const int half = tid >> 7;
    const unsigned long long fm = sflush;
    const char* rm = (const char*)RMbuf;
    float accv = 0.f;
#pragma unroll
    for (int rr = 0; rr < 32; ++rr) {
      int r = half * 32 + rr;
      float v = (float)*(const _Float16*)(rm + (r << 8) + (((col << 1)) ^ ((r & 15) << 4)));
      accv += v;
      if ((fm >> r) & 1ull) {
        atomicAdd(&m_sum[snd[r] * Hc + col], accv * sdinv[r]);
        accv = 0.f;
      }
    }
    if (half == 0 && !((fm >> 31) & 1ull))
      atomicAdd(&m_sum[snd[31] * Hc + col], accv * sdinv[31]);
  }
  __syncthreads();                                   // B5 (scoef complete)
  if (tid < 64) {
    float cf = (scoef[tid] + pb2[lk]) * sdinv[tid];
    float* pp = &p_new[(size_t)snd[tid] * 3];
    atomicAdd(&pp[0], srel[tid][0] * cf);
    atomicAdd(&pp[1], srel[tid][1] * cf);
    atomicAdd(&pp[2], srel[tid][2] * cf);
  }
}

// ---------------- node update kernel (reg-hoisted weights) ----------------

__global__ __launch_bounds__(256, 3)
void update_mfma_kernel(_Float16* __restrict__ h16, const float* __restrict__ m_sum,
                        const _Float16* __restrict__ U1e, const _Float16* __restrict__ U2e,
                        int l) {
  const int tid = threadIdx.x;
  const int wave = tid >> 6, lane = tid & 63;
  const int lrow = lane & 31, lhalf = lane >> 5;
  const int row0 = blockIdx.x << 5;

  __shared__ __align__(16) _Float16 RegA[16 * 512];
  __shared__ __align__(16) _Float16 Mbuf[8 * 512];
  __shared__ __align__(16) _Float16 Dchk[512];

  const _Float16* ub1 = &U1e[(size_t)(l * 4 + wave) * (17 * 512)];
  const _Float16* ub2 = &U2e[(size_t)(l * 4 + wave) * (9 * 512)];
  h8 u1r[17], u2r[9];
#pragma unroll
  for (int t = 0; t < 17; ++t) u1r[t] = *(const h8*)&ub1[t * 512 + lane * 8];
#pragma unroll
  for (int t = 0; t < 9; ++t)  u2r[t] = *(const h8*)&ub2[t * 512 + lane * 8];

  if (tid < 64) {
    h8 dv = (h8)(_Float16)0.f;
    if (tid < 32) dv[1] = (_Float16)1.f;
    *(h8*)&Dchk[tid * 8] = dv;
  }
  {
    const int i = tid & 31, c = tid >> 5;
    size_t hb = (size_t)(row0 + i) * Hc;
    h8 v0 = *(const h8*)&h16[hb + c * 8];
    h8 v1 = *(const h8*)&h16[hb + 64 + c * 8];
    v4 m0 = *(const v4*)&m_sum[hb + c * 8];
    v4 m1 = *(const v4*)&m_sum[hb + c * 8 + 4];
    v4 m2 = *(const v4*)&m_sum[hb + 64 + c * 8];
    v4 m3 = *(const v4*)&m_sum[hb + 64 + c * 8 + 4];
    union { h8 v; h4 q[2]; } w0, w1;
    w0.q[0] = pack4(m0[0], m0[1], m0[2], m0[3]);
    w0.q[1] = pack4(m1[0], m1[1], m1[2], m1[3]);
    w1.q[0] = pack4(m2[0], m2[1], m2[2], m2[3]);
    w1.q[1] = pack4(m3[0], m3[1], m3[2], m3[3]);
    int slot = (i + ((c & 1) << 5)) << 3;
    int tb = (c >> 1) << 9;
    *(h8*)&RegA[tb + slot] = v0;
    *(h8*)&RegA[tb + 4 * 512 + slot] = v1;
    *(h8*)&RegA[tb + 8 * 512 + slot] = w0.v;
    *(h8*)&RegA[tb + 12 * 512 + slot] = w1.v;
  }
  __syncthreads();

  h8 dR = *(const h8*)&Dchk[lane * 8];

  f32x16 acc;
#pragma unroll
  for (int r = 0; r < 16; ++r) acc[r] = 0.f;
#pragma unroll
  for (int t = 0; t < 16; ++t) {
    h8 bact = *(const h8*)&RegA[t * 512 + lane * 8];
    acc = __builtin_amdgcn_mfma_f32_32x32x16_f16(u1r[t], bact, acc, 0, 0, 0);
  }
  acc = __builtin_amdgcn_mfma_f32_32x32x16_f16(u1r[16], dR, acc, 0, 0, 0);
#pragma unroll
  for (int c = 0; c < 4; ++c) {
    h4 u1pk = pack4(silu_f(acc[c * 4 + 0]), silu_f(acc[c * 4 + 1]),
                    silu_f(acc[c * 4 + 2]), silu_f(acc[c * 4 + 3]));
    int t = (wave << 1) + (c >> 1);
    int base = (c & 1) * 256 + lrow * 8 + lhalf * 4;
    *(h4*)&Mbuf[t * 512 + base] = u1pk;
  }
  __syncthreads();

  f32x16 acc2;
#pragma unroll
  for (int r = 0; r < 16; ++r) acc2[r] = 0.f;
#pragma unroll
  for (int t = 0; t < 8; ++t) {
    h8 bact = *(const h8*)&Mbuf[t * 512 + lane * 8];
    acc2 = __builtin_amdgcn_mfma_f32_32x32x16_f16(u2r[t], bact, acc2, 0, 0, 0);
  }
  acc2 = __builtin_amdgcn_mfma_f32_32x32x16_f16(u2r[8], dR, acc2, 0, 0, 0);
  {
    _Float16* hp = &h16[(size_t)(row0 + lrow) * Hc];
#pragma unroll
    for (int c = 0; c < 4; ++c) {
      int hb = (wave << 5) + (c << 3) + (lhalf << 2);
      h4 old = *(const h4*)&hp[hb];
      *(h4*)&hp[hb] = pack4((float)old[0] + acc2[c * 4 + 0], (float)old[1] + acc2[c * 4 + 1],
                            (float)old[2] + acc2[c * 4 + 2], (float)old[3] + acc2[c * 4 + 3]);
    }
  }
}

// ---------------- readout ----------------

__global__ void readout_kernel(const _Float16* __restrict__ h16, const int* __restrict__ ent,
                               const float* __restrict__ oW1, const float* __restrict__ ob1,
                               const float* __restrict__ oW2, const float* __restrict__ ob2,
                               float* __restrict__ out) {
  __shared__ float tb[Bc][Hc];
  int tid = threadIdx.x;
  int b = tid >> 7, j = tid & 127;
  const _Float16* e = &h16[((size_t)(b * Nc + ent[b])) * Hc];
  float a = ob1[j];
#pragma unroll 4
  for (int i = 0; i < Hc; ++i) a = fmaf((float)e[i], oW1[i * Hc + j], a);
  tb[b][j] = silu_f(a);
  __syncthreads();
  if (tid < Bc) {
    float s = ob2[0];
    for (int i = 0; i < Hc; ++i) s = fmaf(tb[tid][i], oW2[i], s);
    out[tid] = s;
  }
}

// ---------------- host launcher ----------------

extern "C" void kernel_launch(void* const* d_in, const int* in_sizes, int n_in,
                              void* d_out, int out_size, void* d_ws, size_t ws_size,
                              hipStream_t stream) {
  const float* x    = (const float*)d_in[0];
  const float* bfe  = (const float*)d_in[1];
  const float* bp   = (const float*)d_in[2];
  const float* Win  = (const float*)d_in[3];
  const float* b_in = (const float*)d_in[4];
  const float* mW1  = (const float*)d_in[5];
  const float* mb1  = (const float*)d_in[6];
  const float* mW2  = (const float*)d_in[7];
  const float* mb2  = (const float*)d_in[8];
  const float* pW1  = (const float*)d_in[9];
  const float* pb1  = (const float*)d_in[10];
  const float* pW2  = (const float*)d_in[11];
  const float* pb2  = (const float*)d_in[12];
  const float* uW1  = (const float*)d_in[13];
  const float* ub1  = (const float*)d_in[14];
  const float* uW2  = (const float*)d_in[15];
  const float* ub2  = (const float*)d_in[16];
  const float* oW1  = (const float*)d_in[17];
  const float* ob1  = (const float*)d_in[18];
  const float* oW2  = (const float*)d_in[19];
  const float* ob2  = (const float*)d_in[20];
  const int* ent    = (const int*)d_in[21];
  const int* esrc   = (const int*)d_in[22];
  const int* edst   = (const int*)d_in[23];

  float* wsf = (float*)d_ws;
  float* msum   = wsf;  wsf += (size_t)Bc * Nc * Hc;
  float* pa     = wsf;  wsf += (size_t)Bc * Nc * 3;
  float* pb_    = wsf;  wsf += (size_t)Bc * Nc * 3;
  float* deginv = wsf;  wsf += (size_t)NBc * Nc;
  _Float16* h16 = (_Float16*)wsf;
  _Float16* W1e = h16 + (size_t)Bc * Nc * Hc;
  _Float16* W2e = W1e + 208896;   // 6*4*17*512
  _Float16* P1e = W2e + 110592;   // 6*4*9*512
  _Float16* U1e = P1e + 110592;
  _Float16* U2e = U1e + 69632;    // 2*4*17*512
  int* hist   = (int*)(U2e + 36864);
  int* cursor = hist + NBc * Nc;
  int* offs   = cursor + NBc * Nc;
  int* sorted = offs + NBc * Nc;

  // --- sort edges by dst (once per call; hist doubles as degree) ---
  zero4_kernel<<<dim3((2 * NBc * Nc / 4 + 255) / 256), dim3(256), 0, stream>>>((float*)hist, 2 * NBc * Nc / 4);
  hist_kernel<<<dim3((NBc * Ec + 255) / 256), dim3(256), 0, stream>>>(hist, edst);
  scan_kernel<<<dim3(NBc), dim3(256), 0, stream>>>(hist, offs, deginv);
  sort_scatter_kernel<<<dim3((NBc * Ec + 255) / 256), dim3(256), 0, stream>>>(sorted, cursor, offs, edst);

  // --- extended weight fragment conversions (bias/d2 rows folded) ---
  conv_ext_kernel<<<dim3(816), dim3(256), 0, stream>>>(W1e, mW1, mb1, 17, 208896, 257, 257);
  conv_ext_kernel<<<dim3(432), dim3(256), 0, stream>>>(W2e, mW2, mb2, 9, 110592, 128, 129);
  conv_ext_kernel<<<dim3(432), dim3(256), 0, stream>>>(P1e, pW1, pb1, 9, 110592, 128, 129);
  conv_ext_kernel<<<dim3(272), dim3(256), 0, stream>>>(U1e, uW1, ub1, 17, 69632, 256, 257);
  conv_ext_kernel<<<dim3(144), dim3(256), 0, stream>>>(U2e, uW2, ub2, 9, 36864, 128, 129);

  init_h_kernel<<<dim3((Bc * Nc * Hc + 255) / 256), dim3(256), 0, stream>>>(h16, bfe, x, Win, b_in, ent);
  init_p_kernel<<<dim3((Bc * Nc * 3 + 255) / 256), dim3(256), 0, stream>>>(pa, bp);

  float* pcur = pa;
  float* pnew = pb_;
  const int nmh = Bc * Nc * Hc;
  for (int l = 0; l < Lc; ++l) {
    zero4_kernel<<<dim3((nmh / 4 + 255) / 256), dim3(256), 0, stream>>>(msum, nmh / 4);
    copy_kernel<<<dim3((Bc * Nc * 3 + 255) / 256), dim3(256), 0, stream>>>(pnew, pcur, Bc * Nc * 3);
    edge_mfma_kernel<<<dim3(Bc * Ec / 64, NBc), dim3(256), 0, stream>>>(
        h16, pcur, msum, pnew, deginv, esrc, edst, sorted,
        W1e, W2e, P1e, pW2, pb2, l);
    update_mfma_kernel<<<dim3(Bc * Nc / 32), dim3(256), 0, stream>>>(h16, msum, U1e, U2e, l);
    float* t = pcur; pcur = pnew; pnew = t;
  }
  readout_kernel<<<dim3(1), dim3(256), 0, stream>>>(h16, ent, oW1, ob1, oW2, ob2, (float*)d_out);
}